// Round 8
// baseline (353.948 us; speedup 1.0000x reference)
//
#include <hip/hip_runtime.h>
#include <hip/hip_bf16.h>

#define SEQ 16384
#define DIM 1280
#define NHEAD 16
#define HD 80
#define NWIN 256   // SEQ / 64
#define QKV_N 3840 // 3 * DIM
#define GK 1280    // K of both GEMMs
#define NT 20      // GK / 64

typedef __attribute__((ext_vector_type(8))) short bf16x8;
typedef __attribute__((ext_vector_type(8))) unsigned short ushort8;
typedef __attribute__((ext_vector_type(4))) float f32x4;
typedef __attribute__((ext_vector_type(16))) float f32x16;

__device__ inline unsigned short f2bf(float x) {
    union { __hip_bfloat16 b; unsigned short u; } cv;
    cv.b = __float2bfloat16(x);
    return cv.u;
}
__device__ inline float bf2f(unsigned short u) {
    union { unsigned int i; float f; } cv;
    cv.i = ((unsigned int)u) << 16;
    return cv.f;
}

// async global->LDS, 16B per lane, wave-uniform LDS base + lane*16
#define GLD16(g, l) __builtin_amdgcn_global_load_lds( \
    (const __attribute__((address_space(1))) void*)(g), \
    (__attribute__((address_space(3))) void*)(l), 16, 0, 0)

#define SBAR() asm volatile("s_barrier" ::: "memory")

// ---------------------------------------------------------------------------
// f32 -> bf16 convert, 8 elems/thread, vectorized
// ---------------------------------------------------------------------------
__global__ __launch_bounds__(256) void cvt_f32_bf16(const float* __restrict__ src,
                                                    unsigned short* __restrict__ dst,
                                                    long n) {
    long i = ((long)blockIdx.x * 256 + threadIdx.x) * 8;
    if (i >= n) return;
    const float4 a = *(const float4*)(src + i);
    const float4 b = *(const float4*)(src + i + 4);
    ushort8 o;
    o[0] = f2bf(a.x); o[1] = f2bf(a.y); o[2] = f2bf(a.z); o[3] = f2bf(a.w);
    o[4] = f2bf(b.x); o[5] = f2bf(b.y); o[6] = f2bf(b.z); o[7] = f2bf(b.w);
    *(ushort8*)(dst + i) = o;
}

// ---------------------------------------------------------------------------
// Fat-wave bf16 MFMA NT-GEMM: out[M][N] = A[M][K] @ B[N][K]^T + bias
// 256x256 tile, BK=64, 256 threads = 4 waves (2Mx2N), per-wave 128x128 out,
// mfma_f32_32x32x16_bf16, acc = 4x4 f32x16 (256 AGPR, 1 wave/SIMD).
// Rationale: r5-r7 all plateaued at ~43% MfmaUtil with 8 thin waves because
// LDS-read bytes/K-tile (196 KB) ~= MFMA time; fat waves double B-reuse ->
// 128 KB/K-tile, putting MFMA (2066 cyc) above LDS (~1550 cyc).
// Single-barrier K-loop (r7): per K-tile one {vmcnt(0); s_barrier}, then
// stage ALL of tile kt+1 into region ~cur, then 4 kslice phases.
// T1 XCD swizzle; T2 XOR swizzle elem ^= (row&7)<<3 (pre-swizzled global
// source + XOR of the FULL k-offset on reads); T5 setprio.
// 32x32 C/D layout: col = lane&31, row = (reg&3)+8*(reg>>2)+4*(lane>>5).
// ---------------------------------------------------------------------------
template <int OUT_BF16>
__global__ __launch_bounds__(256, 1) void gemm_nt_bf16_fw(
    const unsigned short* __restrict__ A,   // [M][GK] bf16
    const unsigned short* __restrict__ B,   // [N][GK] bf16
    const float* __restrict__ bias,         // [N]
    void* __restrict__ outp,                // [M][N] f32 or bf16
    int N, int nbx)                         // nbx = N/256
{
    __shared__ unsigned short sh[65536];    // [2][A 16384 | B 16384] elems, 128 KiB

    const int t = threadIdx.x;
    const int w = t >> 6;
    const int lane = t & 63;
    const int l31 = lane & 31;
    const int g32 = lane >> 5;

    // T1: XCD swizzle (gridDim.x multiple of 8)
    const int cpx = gridDim.x >> 3;
    const int bid = blockIdx.x;
    const int wg = (bid & 7) * cpx + (bid >> 3);
    const int bm = (wg / nbx) * 256;
    const int bn = (wg % nbx) * 256;

    const int wr = (w >> 1) * 128;   // wave rows [wr, wr+128)
    const int wc = (w & 1) * 128;    // wave cols [wc, wc+128)

    // staging: per 32-row block j (A: j=0..7, B: j=0..7), thread t covers
    // row tr = t>>3, 16B slot t&7. Pre-swizzled source col = slot*8 ^ ((tr&7)<<3).
    const int tr = t >> 3;
    const int colsw = ((t & 7) * 8) ^ (((t >> 3) & 7) << 3);  // elements
    const unsigned short* gA = A + (size_t)(bm + tr) * GK + colsw;
    const unsigned short* gB = B + (size_t)(bn + tr) * GK + colsw;
    const int wub = (t & ~63) * 8;   // wave-uniform LDS elem base within a block

    // ds_read frag offsets: LDS[row*64 + e] = global[row][e ^ ((row&7)<<3)]
    // frag (ks, g32) reads e = (ks*16 + g32*8) ^ sw  (XOR of FULL offset)
    const int sw = (l31 & 7) << 3;
    int fk[4];
#pragma unroll
    for (int ks = 0; ks < 4; ++ks) fk[ks] = (ks * 16 + g32 * 8) ^ sw;
    int arow[4], brow[4];
#pragma unroll
    for (int mf = 0; mf < 4; ++mf) arow[mf] = (wr + mf * 32 + l31) * 64;
#pragma unroll
    for (int nf = 0; nf < 4; ++nf) brow[nf] = 16384 + (wc + nf * 32 + l31) * 64;

    f32x16 acc[4][4];
#pragma unroll
    for (int mf = 0; mf < 4; ++mf)
#pragma unroll
        for (int nf = 0; nf < 4; ++nf)
#pragma unroll
            for (int r = 0; r < 16; ++r) acc[mf][nf][r] = 0.f;

    // stage all 16 loads of K-tile `tile` into region tile&1 (64 KB)
    auto stageTile = [&](int tile) {
        if (tile >= NT) return;
        unsigned short* rg = sh + (tile & 1) * 32768 + wub;
        const int ka = tile * 64;
#pragma unroll
        for (int j = 0; j < 8; ++j) {
            GLD16(gA + (size_t)(j * 32) * GK + ka, rg + j * 2048);
            GLD16(gB + (size_t)(j * 32) * GK + ka, rg + 16384 + j * 2048);
        }
    };

    // prologue
    stageTile(0);

    for (int kt = 0; kt < NT; ++kt) {
        const unsigned short* base = sh + (kt & 1) * 32768;

        asm volatile("s_waitcnt vmcnt(0)" ::: "memory");  // tile kt staged
        SBAR();                                           // block-wide visible
        stageTile(kt + 1);                                // region ~cur only

#pragma unroll
        for (int ks = 0; ks < 4; ++ks) {
            bf16x8 af[4], bfr[4];
#pragma unroll
            for (int mf = 0; mf < 4; ++mf)
                af[mf] = *(const bf16x8*)(base + arow[mf] + fk[ks]);
#pragma unroll
            for (int nf = 0; nf < 4; ++nf)
                bfr[nf] = *(const bf16x8*)(base + brow[nf] + fk[ks]);
            __builtin_amdgcn_s_setprio(1);
#pragma unroll
            for (int mf = 0; mf < 4; ++mf)
#pragma unroll
                for (int nf = 0; nf < 4; ++nf)
                    acc[mf][nf] = __builtin_amdgcn_mfma_f32_32x32x16_bf16(
                        af[mf], bfr[nf], acc[mf][nf], 0, 0, 0);
            __builtin_amdgcn_s_setprio(0);
            __builtin_amdgcn_sched_barrier(0);
        }
    }

    // ---- epilogue: C/D col = l31, row = (reg&3) + 8*(reg>>2) + 4*g32 ----
    const int ocol = bn + wc + l31;
    float bv[4];
#pragma unroll
    for (int nf = 0; nf < 4; ++nf) bv[nf] = bias[ocol + nf * 32];
#pragma unroll
    for (int mf = 0; mf < 4; ++mf)
#pragma unroll
        for (int nf = 0; nf < 4; ++nf)
#pragma unroll
            for (int r = 0; r < 16; ++r) {
                const int row = bm + wr + mf * 32 + (r & 3) + 8 * (r >> 2) + 4 * g32;
                const int col = ocol + nf * 32;
                const float v = acc[mf][nf][r] + bv[nf];
                if (OUT_BF16)
                    ((unsigned short*)outp)[(size_t)row * N + col] = f2bf(v);
                else
                    ((float*)outp)[(size_t)row * N + col] = v;
            }
}

// ---------------------------------------------------------------------------
// MFMA windowed attention (unchanged; ~55 us)
// ---------------------------------------------------------------------------
__global__ __launch_bounds__(256) void win_attn_mfma(
    const unsigned short* __restrict__ qkv,  // [S][3840] bf16
    const float* __restrict__ cosb,          // [S][80]
    const float* __restrict__ sinb,          // [S][80]
    const float* __restrict__ mask,          // [NWIN][64][64]
    unsigned short* __restrict__ attn_out)   // [S][1280] bf16
{
    const int h = blockIdx.x;
    const int win = blockIdx.y;
    const int t = threadIdx.x;
    const int w = t >> 6;
    const int lane = t & 63;
    const int l15 = lane & 15;
    const int g = lane >> 4;

    __shared__ unsigned short Qs[64 * 104];
    __shared__ unsigned short Ks[64 * 104];
    __shared__ unsigned short Vt[80 * 88];
    unsigned short* P = Qs;

    const float scale = 0.11180339887498949f;  // 1/sqrt(80)

    for (int c = t; c < 640; c += 256) {
        const int qk = c / 320;
        const int cc = c % 320;
        const int tok = cc / 5;
        const int dd = (cc % 5) * 8;
        const int tokg = win * 64 + tok;
        const size_t gb = (size_t)tokg * QKV_N + h * HD + qk * DIM;
        const bf16x8 lo = *(const bf16x8*)(qkv + gb + dd);
        const bf16x8 hi = *(const bf16x8*)(qkv + gb + dd + 40);
        float cl[8], sl[8], ch[8], sh[8];
        *(float4*)cl = *(const float4*)(cosb + tokg * HD + dd);
        *(float4*)(cl + 4) = *(const float4*)(cosb + tokg * HD + dd + 4);
        *(float4*)sl = *(const float4*)(sinb + tokg * HD + dd);
        *(float4*)(sl + 4) = *(const float4*)(sinb + tokg * HD + dd + 4);
        *(float4*)ch = *(const float4*)(cosb + tokg * HD + dd + 40);
        *(float4*)(ch + 4) = *(const float4*)(cosb + tokg * HD + dd + 44);
        *(float4*)sh = *(const float4*)(sinb + tokg * HD + dd + 40);
        *(float4*)(sh + 4) = *(const float4*)(sinb + tokg * HD + dd + 44);
        ushort8 olo, ohi;
#pragma unroll
        for (int j = 0; j < 8; ++j) {
            const float x1 = bf2f((unsigned short)lo[j]);
            const float x2 = bf2f((unsigned short)hi[j]);
            float rl = x1 * cl[j] - x2 * sl[j];
            float rh = x2 * ch[j] + x1 * sh[j];
            if (qk == 0) { rl *= scale; rh *= scale; }
            olo[j] = f2bf(rl);
            ohi[j] = f2bf(rh);
        }
        unsigned short* base = (qk ? Ks : Qs) + tok * 104 + dd;
        *(ushort8*)base = olo;
        *(ushort8*)(base + 40) = ohi;
    }
    {
        const int tile = t >> 7, row = (t >> 1) & 63, half = t & 1;
        ushort8 z = (ushort8)0;
        *(ushort8*)((tile ? Ks : Qs) + row * 104 + 80 + half * 8) = z;
    }
    for (int c = t; c < 640; c += 256) {
        const int tok = c / 10;
        const int dd = (c % 10) * 8;
        const bf16x8 vv = *(const bf16x8*)(qkv +
            (size_t)(win * 64 + tok) * QKV_N + h * HD + 2 * DIM + dd);
#pragma unroll
        for (int j = 0; j < 8; ++j)
            Vt[(dd + j) * 88 + tok] = (unsigned short)vv[j];
    }
    __syncthreads();

    f32x4 acc[4];
#pragma unroll
    for (int n = 0; n < 4; ++n) acc[n] = (f32x4){0.f, 0.f, 0.f, 0.f};
#pragma unroll
    for (int ks = 0; ks < 3; ++ks) {
        const int k0 = ks * 32;
        const bf16x8 af = *(const bf16x8*)(Qs + (w * 16 + l15) * 104 + k0 + g * 8);
#pragma unroll
        for (int n = 0; n < 4; ++n) {
            const bf16x8 bfr = *(const bf16x8*)(Ks + (n * 16 + l15) * 104 + k0 + g * 8);
            acc[n] = __builtin_amdgcn_mfma_f32_16x16x32_bf16(af, bfr, acc[n], 0, 0, 0);
        }
    }

    const float* mp = mask + (size_t)win * 4096;
    float pr[4][4];
#pragma unroll
    for (int r = 0; r < 4; ++r) {
        const int row = w * 16 + g * 4 + r;
        float v[4];
#pragma unroll
        for (int n = 0; n < 4; ++n)
            v[n] = acc[n][r] + mp[row * 64 + n * 16 + l15];
        float mx = fmaxf(fmaxf(v[0], v[1]), fmaxf(v[2], v[3]));
        mx = fmaxf(mx, __shfl_xor(mx, 1));
        mx = fmaxf(mx, __shfl_xor(mx, 2));
        mx = fmaxf(mx, __shfl_xor(mx, 4));
        mx = fmaxf(mx, __shfl_xor(mx, 8));
        float sum = 0.f;
#pragma unroll
        for (int n = 0; n < 4; ++n) { v[n] = __expf(v[n] - mx); sum += v[n]; }
        sum += __shfl_xor(sum, 1);
        sum += __shfl_xor(sum, 2);
        sum += __shfl_xor(sum, 4);
        sum += __shfl_xor(sum, 8);
        const float inv = 1.0f / sum;
#pragma unroll
        for (int n = 0; n < 4; ++n) pr[r][n] = v[n] * inv;
    }

    __syncthreads();
#pragma unroll
    for (int r = 0; r < 4; ++r)
#pragma unroll
        for (int n = 0; n < 4; ++n)
            P[(w * 16 + g * 4 + r) * 72 + n * 16 + l15] = f2bf(pr[r][n]);
    __syncthreads();

    f32x4 ao[5];
#pragma unroll
    for (int n = 0; n < 5; ++n) ao[n] = (f32x4){0.f, 0.f, 0.f, 0.f};
#pragma unroll
    for (int ks = 0; ks < 2; ++ks) {
        const int k0 = ks * 32;
        const bf16x8 pa = *(const bf16x8*)(P + (w * 16 + l15) * 72 + k0 + g * 8);
#pragma unroll
        for (int n = 0; n < 5; ++n) {
            const bf16x8 bv = *(const bf16x8*)(Vt + (n * 16 + l15) * 88 + k0 + g * 8);
            ao[n] = __builtin_amdgcn_mfma_f32_16x16x32_bf16(pa, bv, ao[n], 0, 0, 0);
        }
    }

#pragma unroll
    for (int n = 0; n < 5; ++n)
#pragma unroll
        for (int r = 0; r < 4; ++r) {
            const int row = win * 64 + w * 16 + g * 4 + r;
            attn_out[(size_t)row * DIM + h * HD + n * 16 + l15] = f2bf(ao[n][r]);
        }
}

// ---------------------------------------------------------------------------
extern "C" void kernel_launch(void* const* d_in, const int* in_sizes, int n_in,
                              void* d_out, int out_size, void* d_ws, size_t ws_size,
                              hipStream_t stream) {
    const float* hidden = (const float*)d_in[0];
    const float* masks  = (const float*)d_in[1];
    const float* cosb   = (const float*)d_in[2];
    const float* sinb   = (const float*)d_in[3];
    const float* qkv_w  = (const float*)d_in[4];
    const float* qkv_b  = (const float*)d_in[5];
    const float* proj_w = (const float*)d_in[6];
    const float* proj_b = (const float*)d_in[7];
    float* out = (float*)d_out;

    unsigned short* qkv_bf    = (unsigned short*)d_ws;                  // [SEQ][3840]
    unsigned short* attn_bf   = qkv_bf    + (size_t)SEQ * QKV_N;        // [SEQ][1280]
    unsigned short* hidden_bf = attn_bf   + (size_t)SEQ * DIM;          // [SEQ][1280]
    unsigned short* qkvw_bf   = hidden_bf + (size_t)SEQ * DIM;          // [3840][1280]
    unsigned short* projw_bf  = qkvw_bf   + (size_t)QKV_N * DIM;        // [1280][1280]

    {
        const long n0 = (long)SEQ * DIM;
        const long n1 = (long)QKV_N * DIM;
        const long n2 = (long)DIM * DIM;
        cvt_f32_bf16<<<(int)(n0 / (8 * 256)), 256, 0, stream>>>(hidden, hidden_bf, n0);
        cvt_f32_bf16<<<(int)(n1 / (8 * 256)), 256, 0, stream>>>(qkv_w, qkvw_bf, n1);
        cvt_f32_bf16<<<(int)(n2 / (8 * 256)), 256, 0, stream>>>(proj_w, projw_bf, n2);
    }
    {   // QKV projection: M=16384, N=3840 -> 64x15 = 960 blocks (%8==0)
        gemm_nt_bf16_fw<1><<<dim3(960), 256, 0, stream>>>(
            hidden_bf, qkvw_bf, qkv_b, (void*)qkv_bf, QKV_N, QKV_N / 256);
    }
    {
        dim3 grid(NHEAD, NWIN);
        win_attn_mfma<<<grid, 256, 0, stream>>>(qkv_bf, cosb, sinb, masks, attn_bf);
    }
    {   // output projection: M=16384, N=1280 -> 64x5 = 320 blocks (%8==0)
        gemm_nt_bf16_fw<0><<<dim3(320), 256, 0, stream>>>(
            attn_bf, projw_bf, proj_b, (void*)out, DIM, DIM / 256);
    }
}

// Round 9
// 326.935 us; speedup vs baseline: 1.0826x; 1.0826x over previous
//
#include <hip/hip_runtime.h>
#include <hip/hip_bf16.h>

#define SEQ 16384
#define DIM 1280
#define NHEAD 16
#define HD 80
#define NWIN 256   // SEQ / 64
#define QKV_N 3840 // 3 * DIM
#define GK 1280    // K of both GEMMs
#define NT 20      // GK / 64

typedef __attribute__((ext_vector_type(8))) short bf16x8;
typedef __attribute__((ext_vector_type(8))) unsigned short ushort8;
typedef __attribute__((ext_vector_type(4))) float f32x4;

__device__ inline unsigned short f2bf(float x) {
    union { __hip_bfloat16 b; unsigned short u; } cv;
    cv.b = __float2bfloat16(x);
    return cv.u;
}
__device__ inline float bf2f(unsigned short u) {
    union { unsigned int i; float f; } cv;
    cv.i = ((unsigned int)u) << 16;
    return cv.f;
}

// async global->LDS, 16B per lane, wave-uniform LDS base + lane*16
#define GLD16(g, l) __builtin_amdgcn_global_load_lds( \
    (const __attribute__((address_space(1))) void*)(g), \
    (__attribute__((address_space(3))) void*)(l), 16, 0, 0)

#define SBAR() asm volatile("s_barrier" ::: "memory")

// ---------------------------------------------------------------------------
// f32 -> bf16 convert, 8 elems/thread, vectorized
// ---------------------------------------------------------------------------
__global__ __launch_bounds__(256) void cvt_f32_bf16(const float* __restrict__ src,
                                                    unsigned short* __restrict__ dst,
                                                    long n) {
    long i = ((long)blockIdx.x * 256 + threadIdx.x) * 8;
    if (i >= n) return;
    const float4 a = *(const float4*)(src + i);
    const float4 b = *(const float4*)(src + i + 4);
    ushort8 o;
    o[0] = f2bf(a.x); o[1] = f2bf(a.y); o[2] = f2bf(a.z); o[3] = f2bf(a.w);
    o[4] = f2bf(b.x); o[5] = f2bf(b.y); o[6] = f2bf(b.z); o[7] = f2bf(b.w);
    *(ushort8*)(dst + i) = o;
}

// ---------------------------------------------------------------------------
// Software-pipelined single-barrier bf16 MFMA NT-GEMM (r7 base, r9 overlap):
// out[M][N] = A[M][K] @ B[N][K]^T + bias
// 256x256 tile, BK=64, 512 threads (8 waves 2Mx4N, 128x64 out each),
// mfma_f32_16x16x32_bf16 (thin-wave: conflict-free with 3-bit swizzle,
// measured 0 conflicts r5-r7; 32x32 fat-wave regressed, r8).
// Per K-tile: one {vmcnt(0); s_barrier}; stage ALL of tile kt+1 into region
// ~cur; then 4 MFMA quads with PING-PONG frag sets — next phase's ds_reads
// issue BEFORE the current MFMA quad and NO sched_barrier pins the order,
// so the compiler emits partial lgkmcnt waits and LDS reads run under MFMAs
// (r5-r8 plateau = serial LDS/MFMA pipes; r7's sched_barrier(0) caused it).
// Race-freedom as r7: stage targets only region ~cur; W->R fenced by next
// iter's vmcnt(0)+barrier; R->W by reads retiring before barrier arrival.
// T1 XCD swizzle; T2 both-sides XOR swizzle (elem ^= (row&7)<<3, XOR of the
// FULL k-offset); T5 setprio.
// ---------------------------------------------------------------------------
template <int OUT_BF16>
__global__ __launch_bounds__(512, 2) void gemm_nt_bf16_sp(
    const unsigned short* __restrict__ A,   // [M][GK] bf16
    const unsigned short* __restrict__ B,   // [N][GK] bf16
    const float* __restrict__ bias,         // [N]
    void* __restrict__ outp,                // [M][N] f32 or bf16
    int N, int nbx)                         // nbx = N/256
{
    __shared__ unsigned short sh[65536];    // [2][A 16384 | B 16384], 128 KiB

    const int t = threadIdx.x;
    const int w = t >> 6;
    const int lane = t & 63;
    const int l15 = lane & 15;
    const int g = lane >> 4;

    // T1: XCD swizzle (gridDim.x multiple of 8)
    const int cpx = gridDim.x >> 3;
    const int bid = blockIdx.x;
    const int wg = (bid & 7) * cpx + (bid >> 3);
    const int bm = (wg / nbx) * 256;
    const int bn = (wg % nbx) * 256;

    const int wr = (w >> 2) * 128;   // wave rows [wr, wr+128)
    const int wc = (w & 3) * 64;     // wave cols [wc, wc+64)

    // staging: thread t covers 16B chunk (row = t>>3 within 64-row block j,
    // slot = t&7); pre-swizzled source col = slot*8 ^ ((row&7)<<3)
    const int tr = t >> 3;
    const int colsw = ((t & 7) * 8) ^ (((t >> 3) & 7) << 3);  // elements
    const unsigned short* gA[4];
    const unsigned short* gB[4];
#pragma unroll
    for (int j = 0; j < 4; ++j) {
        gA[j] = A + (size_t)(bm + j * 64 + tr) * GK + colsw;
        gB[j] = B + (size_t)(bn + j * 64 + tr) * GK + colsw;
    }
    const int wub = (t & ~63) * 8;   // wave-uniform LDS elem base

    // ds_read frag offsets: LDS[row*64 + e] = global[row][e ^ ((row&7)<<3)]
    // fragment k-chunk kk reads e = (kk*32 + g*8) ^ sw  (XOR of FULL offset)
    const int sw = (l15 & 7) << 3;
    const int fk0 = (g * 8) ^ sw;
    const int fk1 = (32 + g * 8) ^ sw;
    int arow[8], brow[4];
#pragma unroll
    for (int mi = 0; mi < 8; ++mi) arow[mi] = (wr + mi * 16 + l15) * 64;
#pragma unroll
    for (int ni = 0; ni < 4; ++ni) brow[ni] = 16384 + (wc + ni * 16 + l15) * 64;

    f32x4 acc[8][4];
#pragma unroll
    for (int mi = 0; mi < 8; ++mi)
#pragma unroll
        for (int ni = 0; ni < 4; ++ni)
            acc[mi][ni] = (f32x4){0.f, 0.f, 0.f, 0.f};

    // stage all 8 loads of K-tile `tile` into region tile&1
    auto stageTile = [&](int tile) {
        if (tile >= NT) return;
        unsigned short* rg = sh + (tile & 1) * 32768 + wub;
        const int ka = tile * 64;
        GLD16(gA[0] + ka, rg);
        GLD16(gA[1] + ka, rg + 4096);
        GLD16(gA[2] + ka, rg + 8192);
        GLD16(gA[3] + ka, rg + 12288);
        GLD16(gB[0] + ka, rg + 16384);
        GLD16(gB[1] + ka, rg + 20480);
        GLD16(gB[2] + ka, rg + 24576);
        GLD16(gB[3] + ka, rg + 28672);
    };

    bf16x8 afA[4], afB[4], bfrA[4], bfrB[4];

#define MFMA_QUAD(H, AF, BF)                                                  \
    __builtin_amdgcn_s_setprio(1);                                            \
    _Pragma("unroll") for (int mi = 0; mi < 4; ++mi)                          \
    _Pragma("unroll") for (int ni = 0; ni < 4; ++ni)                          \
        acc[(H) * 4 + mi][ni] = __builtin_amdgcn_mfma_f32_16x16x32_bf16(      \
            (AF)[mi], (BF)[ni], acc[(H) * 4 + mi][ni], 0, 0, 0);              \
    __builtin_amdgcn_s_setprio(0);

    // prologue: stage tile 0
    stageTile(0);

    for (int kt = 0; kt < NT; ++kt) {
        const unsigned short* base = sh + (kt & 1) * 32768;

        asm volatile("s_waitcnt vmcnt(0)" ::: "memory");  // tile kt staged
        SBAR();                                           // block-wide visible
        stageTile(kt + 1);                                // region ~cur only

        // ---- software-pipelined phases (no sched_barrier: let the
        //      compiler run next phase's ds_reads under current MFMAs) ----
#pragma unroll
        for (int ni = 0; ni < 4; ++ni) bfrA[ni] = *(const bf16x8*)(base + brow[ni] + fk0);
#pragma unroll
        for (int mi = 0; mi < 4; ++mi) afA[mi] = *(const bf16x8*)(base + arow[mi] + fk0);

        // ph0 (h0,kk0): prefetch ph1 A, then MFMA
#pragma unroll
        for (int mi = 0; mi < 4; ++mi) afB[mi] = *(const bf16x8*)(base + arow[4 + mi] + fk0);
        MFMA_QUAD(0, afA, bfrA);

        // ph1 (h1,kk0): prefetch ph2 A+B (kk1), then MFMA
#pragma unroll
        for (int ni = 0; ni < 4; ++ni) bfrB[ni] = *(const bf16x8*)(base + brow[ni] + fk1);
#pragma unroll
        for (int mi = 0; mi < 4; ++mi) afA[mi] = *(const bf16x8*)(base + arow[mi] + fk1);
        MFMA_QUAD(1, afB, bfrA);

        // ph2 (h0,kk1): prefetch ph3 A, then MFMA
#pragma unroll
        for (int mi = 0; mi < 4; ++mi) afB[mi] = *(const bf16x8*)(base + arow[4 + mi] + fk1);
        MFMA_QUAD(0, afA, bfrB);

        // ph3 (h1,kk1)
        MFMA_QUAD(1, afB, bfrB);
    }
#undef MFMA_QUAD

    // ---- epilogue: C/D layout col=l15, row=g*4+reg ----
    const int orow = bm + wr + g * 4;
    const int ocol = bn + wc + l15;
    float bv[4];
#pragma unroll
    for (int ni = 0; ni < 4; ++ni) bv[ni] = bias[ocol + ni * 16];
#pragma unroll
    for (int mi = 0; mi < 8; ++mi)
#pragma unroll
        for (int ni = 0; ni < 4; ++ni)
#pragma unroll
            for (int r = 0; r < 4; ++r) {
                const int row = orow + mi * 16 + r;
                const int col = ocol + ni * 16;
                const float v = acc[mi][ni][r] + bv[ni];
                if (OUT_BF16)
                    ((unsigned short*)outp)[(size_t)row * N + col] = f2bf(v);
                else
                    ((float*)outp)[(size_t)row * N + col] = v;
            }
}

// ---------------------------------------------------------------------------
// MFMA windowed attention (unchanged; ~55 us)
// ---------------------------------------------------------------------------
__global__ __launch_bounds__(256) void win_attn_mfma(
    const unsigned short* __restrict__ qkv,  // [S][3840] bf16
    const float* __restrict__ cosb,          // [S][80]
    const float* __restrict__ sinb,          // [S][80]
    const float* __restrict__ mask,          // [NWIN][64][64]
    unsigned short* __restrict__ attn_out)   // [S][1280] bf16
{
    const int h = blockIdx.x;
    const int win = blockIdx.y;
    const int t = threadIdx.x;
    const int w = t >> 6;
    const int lane = t & 63;
    const int l15 = lane & 15;
    const int g = lane >> 4;

    __shared__ unsigned short Qs[64 * 104];
    __shared__ unsigned short Ks[64 * 104];
    __shared__ unsigned short Vt[80 * 88];
    unsigned short* P = Qs;

    const float scale = 0.11180339887498949f;  // 1/sqrt(80)

    for (int c = t; c < 640; c += 256) {
        const int qk = c / 320;
        const int cc = c % 320;
        const int tok = cc / 5;
        const int dd = (cc % 5) * 8;
        const int tokg = win * 64 + tok;
        const size_t gb = (size_t)tokg * QKV_N + h * HD + qk * DIM;
        const bf16x8 lo = *(const bf16x8*)(qkv + gb + dd);
        const bf16x8 hi = *(const bf16x8*)(qkv + gb + dd + 40);
        float cl[8], sl[8], ch[8], sh[8];
        *(float4*)cl = *(const float4*)(cosb + tokg * HD + dd);
        *(float4*)(cl + 4) = *(const float4*)(cosb + tokg * HD + dd + 4);
        *(float4*)sl = *(const float4*)(sinb + tokg * HD + dd);
        *(float4*)(sl + 4) = *(const float4*)(sinb + tokg * HD + dd + 4);
        *(float4*)ch = *(const float4*)(cosb + tokg * HD + dd + 40);
        *(float4*)(ch + 4) = *(const float4*)(cosb + tokg * HD + dd + 44);
        *(float4*)sh = *(const float4*)(sinb + tokg * HD + dd + 40);
        *(float4*)(sh + 4) = *(const float4*)(sinb + tokg * HD + dd + 44);
        ushort8 olo, ohi;
#pragma unroll
        for (int j = 0; j < 8; ++j) {
            const float x1 = bf2f((unsigned short)lo[j]);
            const float x2 = bf2f((unsigned short)hi[j]);
            float rl = x1 * cl[j] - x2 * sl[j];
            float rh = x2 * ch[j] + x1 * sh[j];
            if (qk == 0) { rl *= scale; rh *= scale; }
            olo[j] = f2bf(rl);
            ohi[j] = f2bf(rh);
        }
        unsigned short* base = (qk ? Ks : Qs) + tok * 104 + dd;
        *(ushort8*)base = olo;
        *(ushort8*)(base + 40) = ohi;
    }
    {
        const int tile = t >> 7, row = (t >> 1) & 63, half = t & 1;
        ushort8 z = (ushort8)0;
        *(ushort8*)((tile ? Ks : Qs) + row * 104 + 80 + half * 8) = z;
    }
    for (int c = t; c < 640; c += 256) {
        const int tok = c / 10;
        const int dd = (c % 10) * 8;
        const bf16x8 vv = *(const bf16x8*)(qkv +
            (size_t)(win * 64 + tok) * QKV_N + h * HD + 2 * DIM + dd);
#pragma unroll
        for (int j = 0; j < 8; ++j)
            Vt[(dd + j) * 88 + tok] = (unsigned short)vv[j];
    }
    __syncthreads();

    f32x4 acc[4];
#pragma unroll
    for (int n = 0; n < 4; ++n) acc[n] = (f32x4){0.f, 0.f, 0.f, 0.f};
#pragma unroll
    for (int ks = 0; ks < 3; ++ks) {
        const int k0 = ks * 32;
        const bf16x8 af = *(const bf16x8*)(Qs + (w * 16 + l15) * 104 + k0 + g * 8);
#pragma unroll
        for (int n = 0; n < 4; ++n) {
            const bf16x8 bfr = *(const bf16x8*)(Ks + (n * 16 + l15) * 104 + k0 + g * 8);
            acc[n] = __builtin_amdgcn_mfma_f32_16x16x32_bf16(af, bfr, acc[n], 0, 0, 0);
        }
    }

    const float* mp = mask + (size_t)win * 4096;
    float pr[4][4];
#pragma unroll
    for (int r = 0; r < 4; ++r) {
        const int row = w * 16 + g * 4 + r;
        float v[4];
#pragma unroll
        for (int n = 0; n < 4; ++n)
            v[n] = acc[n][r] + mp[row * 64 + n * 16 + l15];
        float mx = fmaxf(fmaxf(v[0], v[1]), fmaxf(v[2], v[3]));
        mx = fmaxf(mx, __shfl_xor(mx, 1));
        mx = fmaxf(mx, __shfl_xor(mx, 2));
        mx = fmaxf(mx, __shfl_xor(mx, 4));
        mx = fmaxf(mx, __shfl_xor(mx, 8));
        float sum = 0.f;
#pragma unroll
        for (int n = 0; n < 4; ++n) { v[n] = __expf(v[n] - mx); sum += v[n]; }
        sum += __shfl_xor(sum, 1);
        sum += __shfl_xor(sum, 2);
        sum += __shfl_xor(sum, 4);
        sum += __shfl_xor(sum, 8);
        const float inv = 1.0f / sum;
#pragma unroll
        for (int n = 0; n < 4; ++n) pr[r][n] = v[n] * inv;
    }

    __syncthreads();
#pragma unroll
    for (int r = 0; r < 4; ++r)
#pragma unroll
        for (int n = 0; n < 4; ++n)
            P[(w * 16 + g * 4 + r) * 72 + n * 16 + l15] = f2bf(pr[r][n]);
    __syncthreads();

    f32x4 ao[5];
#pragma unroll
    for (int n = 0; n < 5; ++n) ao[n] = (f32x4){0.f, 0.f, 0.f, 0.f};
#pragma unroll
    for (int ks = 0; ks < 2; ++ks) {
        const int k0 = ks * 32;
        const bf16x8 pa = *(const bf16x8*)(P + (w * 16 + l15) * 72 + k0 + g * 8);
#pragma unroll
        for (int n = 0; n < 5; ++n) {
            const bf16x8 bv = *(const bf16x8*)(Vt + (n * 16 + l15) * 88 + k0 + g * 8);
            ao[n] = __builtin_amdgcn_mfma_f32_16x16x32_bf16(pa, bv, ao[n], 0, 0, 0);
        }
    }

#pragma unroll
    for (int n = 0; n < 5; ++n)
#pragma unroll
        for (int r = 0; r < 4; ++r) {
            const int row = win * 64 + w * 16 + g * 4 + r;
            attn_out[(size_t)row * DIM + h * HD + n * 16 + l15] = f2bf(ao[n][r]);
        }
}

// ---------------------------------------------------------------------------
extern "C" void kernel_launch(void* const* d_in, const int* in_sizes, int n_in,
                              void* d_out, int out_size, void* d_ws, size_t ws_size,
                              hipStream_t stream) {
    const float* hidden = (const float*)d_in[0];
    const float* masks  = (const float*)d_in[1];
    const float* cosb   = (const float*)d_in[2];
    const float* sinb   = (const float*)d_in[3];
    const float* qkv_w  = (const float*)d_in[4];
    const float* qkv_b  = (const float*)d_in[5];
    const float* proj_w = (const float*)d_in[6];
    const float* proj_b = (const float*)d_in[7];
    float* out = (float*)d_out;

    unsigned short* qkv_bf    = (unsigned short*)d_ws;                  // [SEQ][3840]
    unsigned short* attn_bf   = qkv_bf    + (size_t)SEQ * QKV_N;        // [SEQ][1280]
    unsigned short* hidden_bf = attn_bf   + (size_t)SEQ * DIM;          // [SEQ][1280]
    unsigned short* qkvw_bf   = hidden_bf + (size_t)SEQ * DIM;          // [3840][1280]
    unsigned short* projw_bf  = qkvw_bf   + (size_t)QKV_N * DIM;        // [1280][1280]

    {
        const long n0 = (long)SEQ * DIM;
        const long n1 = (long)QKV_N * DIM;
        const long n2 = (long)DIM * DIM;
        cvt_f32_bf16<<<(int)(n0 / (8 * 256)), 256, 0, stream>>>(hidden, hidden_bf, n0);
        cvt_f32_bf16<<<(int)(n1 / (8 * 256)), 256, 0, stream>>>(qkv_w, qkvw_bf, n1);
        cvt_f32_bf16<<<(int)(n2 / (8 * 256)), 256, 0, stream>>>(proj_w, projw_bf, n2);
    }
    {   // QKV projection: M=16384, N=3840 -> 64x15 = 960 blocks (%8==0)
        gemm_nt_bf16_sp<1><<<dim3(960), 512, 0, stream>>>(
            hidden_bf, qkvw_bf, qkv_b, (void*)qkv_bf, QKV_N, QKV_N / 256);
    }
    {
        dim3 grid(NHEAD, NWIN);
        win_attn_mfma<<<grid, 256, 0, stream>>>(qkv_bf, cosb, sinb, masks, attn_bf);
    }
    {   // output projection: M=16384, N=1280 -> 64x5 = 320 blocks (%8==0)
        gemm_nt_bf16_sp<0><<<dim3(320), 512, 0, stream>>>(
            attn_bf, projw_bf, proj_b, (void*)out, DIM, DIM / 256);
    }
}